// Round 2
// baseline (815.557 us; speedup 1.0000x reference)
//
#include <hip/hip_runtime.h>
#include <hip/hip_bf16.h>
#include <math.h>

// Problem constants
#define DM    1024          // d_model
#define NE    8             // experts
#define DF    4096          // d_ff
#define NT    4096          // tokens = B*S = 2*2048
#define RCAP  9216          // padded row capacity: 8192 + 8*128
#define OUT_N   (NT*DM)     // 4,194,304
#define DISP_N  (NT*NE)     // 32,768
#define TOTAL_OUT (OUT_N + DISP_N + NE)

typedef __attribute__((ext_vector_type(4))) float f32x4;
typedef __attribute__((ext_vector_type(8))) short bf16x8;

// ---------------- ws layout (bytes) ----------------
#define WS_CNT    0            // int[8]
#define WS_FILL   32           // int[8]
#define WS_OFFS   64           // int[9]
#define WS_TOK    128          // int[RCAP]
#define WS_WGT    (WS_TOK + RCAP*4)          // float[RCAP]
#define WS_TOPE   (WS_WGT + RCAP*4)          // int[NT*2]
#define WS_TOPV   (WS_TOPE + NT*2*4)         // float[NT*2]
#define WS_W1T    (((WS_TOPV + NT*2*4) + 255) & ~255ul)   // bf16[NE][DF][DM]
#define WS_W2T    (WS_W1T + (size_t)NE*DF*DM*2)           // bf16[NE][DM][DF]
#define WS_XG     (WS_W2T + (size_t)NE*DM*DF*2)           // bf16[RCAP][DM]
#define WS_H      (WS_XG  + (size_t)RCAP*DM*2)            // bf16[RCAP][DF]

__device__ __forceinline__ void async_copy16(const __hip_bfloat16* g, __hip_bfloat16* l) {
    __builtin_amdgcn_global_load_lds(
        (const __attribute__((address_space(1))) unsigned int*)g,
        (__attribute__((address_space(3))) unsigned int*)l, 16, 0, 0);
}

// ---------------- init: zero d_out, reset routing scratch ----------------
__global__ void init_kernel(float* __restrict__ out, int* __restrict__ cnt,
                            int* __restrict__ fill, int* __restrict__ tok) {
    int gid = blockIdx.x * blockDim.x + threadIdx.x;
    int stride = gridDim.x * blockDim.x;
    for (int i = gid; i < TOTAL_OUT; i += stride) out[i] = 0.0f;
    if (gid < RCAP) tok[gid] = -1;
    if (gid < NE) { cnt[gid] = 0; fill[gid] = 0; }
}

// ---------------- transpose+cast v2: in[e][R][C] f32 -> out[e][C][R] bf16 ----------------
// 64x64 tiles, float4 loads, ushort4 stores. LDS stored transposed [c][r], row pad 72.
__global__ __launch_bounds__(256) void transpose_cast2(const float* __restrict__ in,
                                                       __hip_bfloat16* __restrict__ outp,
                                                       int R, int C) {
    __shared__ ushort tile[64][72];
    int e = blockIdx.z;
    int c0 = blockIdx.x * 64, r0 = blockIdx.y * 64;
    const float* ib = in + (size_t)e * R * C;
    ushort* ob = (ushort*)outp + (size_t)e * R * C;
    int tx = threadIdx.x & 15, ty = threadIdx.x >> 4;   // 16 x 16
    #pragma unroll
    for (int j = 0; j < 4; ++j) {
        int row = ty + 16 * j;
        float4 v = *(const float4*)(ib + (size_t)(r0 + row) * C + c0 + tx * 4);
        tile[tx * 4 + 0][row] = __bfloat16_as_ushort(__float2bfloat16(v.x));
        tile[tx * 4 + 1][row] = __bfloat16_as_ushort(__float2bfloat16(v.y));
        tile[tx * 4 + 2][row] = __bfloat16_as_ushort(__float2bfloat16(v.z));
        tile[tx * 4 + 3][row] = __bfloat16_as_ushort(__float2bfloat16(v.w));
    }
    __syncthreads();
    #pragma unroll
    for (int j = 0; j < 4; ++j) {
        int cc = ty + 16 * j;
        *(ushort4*)(ob + (size_t)(c0 + cc) * R + r0 + tx * 4) = *(const ushort4*)&tile[cc][tx * 4];
    }
}

// ---------------- gating: 1 wave per token, f64 logits ----------------
__global__ void gate_kernel(const float* __restrict__ x, const float* __restrict__ gw,
                            const float* __restrict__ gb, float* __restrict__ disp,
                            float* __restrict__ counts, int* __restrict__ cnt,
                            int* __restrict__ tope, float* __restrict__ topv) {
    int t = blockIdx.x;
    int l = threadIdx.x;   // 64
    const float* xr = x + (size_t)t * DM;
    double p[NE];
    #pragma unroll
    for (int e = 0; e < NE; ++e) p[e] = 0.0;
    for (int i = 0; i < DM / 64; ++i) {
        int d = l + 64 * i;
        double xv = (double)xr[d];
        const float* gr = gw + (size_t)d * NE;
        #pragma unroll
        for (int e = 0; e < NE; ++e) p[e] += xv * (double)gr[e];
    }
    #pragma unroll
    for (int off = 32; off > 0; off >>= 1) {
        #pragma unroll
        for (int e = 0; e < NE; ++e) p[e] += __shfl_xor(p[e], off, 64);
    }
    if (l == 0) {
        double lg[NE];
        double m = -1e300;
        #pragma unroll
        for (int e = 0; e < NE; ++e) { lg[e] = p[e] + (double)gb[e]; m = fmax(m, lg[e]); }
        double s = 0.0;
        #pragma unroll
        for (int e = 0; e < NE; ++e) s += exp(lg[e] - m);
        int e1 = 0;
        #pragma unroll
        for (int e = 1; e < NE; ++e) if (lg[e] > lg[e1]) e1 = e;
        int e2 = (e1 == 0) ? 1 : 0;
        #pragma unroll
        for (int e = 0; e < NE; ++e) if (e != e1 && lg[e] > lg[e2]) e2 = e;
        float v1 = (float)(exp(lg[e1] - m) / s);
        float v2 = (float)(exp(lg[e2] - m) / s);
        float* dr = disp + (size_t)t * NE;
        #pragma unroll
        for (int e = 0; e < NE; ++e) dr[e] = 0.0f;
        dr[e1] = v1; dr[e2] = v2;
        atomicAdd(&counts[e1], v1);
        atomicAdd(&counts[e2], v2);
        atomicAdd(&cnt[e1], 1);
        atomicAdd(&cnt[e2], 1);
        tope[2 * t] = e1;     topv[2 * t] = v1;
        tope[2 * t + 1] = e2; topv[2 * t + 1] = v2;
    }
}

// ---------------- scan: 128-aligned exclusive prefix ----------------
__global__ void scan_kernel(const int* __restrict__ cnt, int* __restrict__ offs) {
    if (threadIdx.x == 0 && blockIdx.x == 0) {
        int o = 0;
        for (int e = 0; e < NE; ++e) {
            offs[e] = o;
            o += (cnt[e] + 127) & ~127;
        }
        offs[NE] = o;
    }
}

// ---------------- build per-expert row lists ----------------
__global__ void build_kernel(const int* __restrict__ tope, const float* __restrict__ topv,
                             const int* __restrict__ offs, int* __restrict__ fill,
                             int* __restrict__ tok, float* __restrict__ wgt) {
    int t = blockIdx.x * blockDim.x + threadIdx.x;
    if (t >= NT) return;
    #pragma unroll
    for (int s = 0; s < 2; ++s) {
        int e = tope[2 * t + s];
        int pos = atomicAdd(&fill[e], 1);
        int row = offs[e] + pos;
        tok[row] = t;
        wgt[row] = topv[2 * t + s];
    }
}

// ---------------- gather x rows -> bf16 ----------------
__global__ void gather_kernel(const float* __restrict__ x, const int* __restrict__ tok,
                              __hip_bfloat16* __restrict__ xg) {
    int row = blockIdx.x;
    int t = tok[row];
    if (t < 0) return;
    int i = threadIdx.x;   // 256, 4 elems each
    const float4 v = ((const float4*)(x + (size_t)t * DM))[i];
    ushort4 o;
    o.x = __bfloat16_as_ushort(__float2bfloat16(v.x));
    o.y = __bfloat16_as_ushort(__float2bfloat16(v.y));
    o.z = __bfloat16_as_ushort(__float2bfloat16(v.z));
    o.w = __bfloat16_as_ushort(__float2bfloat16(v.w));
    ((ushort4*)(xg + (size_t)row * DM))[i] = o;
}

// ================= GEMM core: 128x128 tile, BK=64, 4 waves, XOR-swizzled LDS =================
// A: bf16 [rows][K]; B: bf16 [N][K] (pre-transposed). Both K-contiguous, stride = K.
// LDS tile [128 rows][64 k] bf16 (128 B/row = 8 x 16B slots). Swizzle: LDS[row][slot] holds
// global slot (slot ^ (row&7)); achieved by pre-swizzling the global SOURCE lane address
// (global_load_lds writes linear base + lane*16). Reads apply the same XOR -> 2-way max.

// GEMM1: h = gelu(xg @ w1 + b1), K=DM, N=DF
__global__ __launch_bounds__(256) void gemm1_kernel(
    const __hip_bfloat16* __restrict__ xg, const __hip_bfloat16* __restrict__ w1t,
    const float* __restrict__ b1, __hip_bfloat16* __restrict__ h,
    const int* __restrict__ offs, const int* __restrict__ cnt) {
    __shared__ __attribute__((aligned(128))) __hip_bfloat16 As[128 * 64];
    __shared__ __attribute__((aligned(128))) __hip_bfloat16 Bs[128 * 64];
    const int NXT = DF / 128;                 // 32 n-tiles
    const int nwg = NXT * (RCAP / 128);       // 2304, %8==0
    int wg = (int)blockIdx.x;
    int id = (wg & 7) * (nwg >> 3) + (wg >> 3);   // XCD-chunked swizzle (bijective)
    const int bx = id % NXT, by = id / NXT;
    const int row0 = by * 128;
    const int total = offs[NE];
    if (row0 >= total) return;
    int e = 0;
    while (row0 >= offs[e + 1]) ++e;
    if (row0 >= offs[e] + cnt[e]) return;     // tile entirely padding
    const int n0 = bx * 128;
    const __hip_bfloat16* Ab = xg + (size_t)row0 * DM;
    const __hip_bfloat16* Bb = w1t + (size_t)e * DF * DM + (size_t)n0 * DM;

    const int tid = threadIdx.x, lane = tid & 63, wave = tid >> 6;
    const int wm = wave >> 1, wn = wave & 1, g = lane >> 4, r = lane & 15;
    const int rr = lane >> 3;                       // row-in-instance 0..7
    const int kx = (((lane & 7) ^ rr) << 3);        // swizzled src k-offset (elems)
    // per-thread staging offsets (4 instances of 8 rows each, per operand)
    size_t soff[4]; int doff[4];
    #pragma unroll
    for (int qi = 0; qi < 4; ++qi) {
        int q = wave * 4 + qi;
        soff[qi] = (size_t)(q * 8 + rr) * DM + kx;
        doff[qi] = q * 512 + lane * 8;
    }
    // fragment read bases
    int rowA[4], rowB[4], tsw[2];
    #pragma unroll
    for (int m = 0; m < 4; ++m) rowA[m] = (wm * 64 + m * 16 + r) * 64;
    #pragma unroll
    for (int n = 0; n < 4; ++n) rowB[n] = (wn * 64 + n * 16 + r) * 64;
    tsw[0] = ((g ^ (r & 7)) << 3);
    tsw[1] = (((4 + g) ^ (r & 7)) << 3);

    f32x4 acc[4][4];
    #pragma unroll
    for (int m = 0; m < 4; ++m)
        #pragma unroll
        for (int n = 0; n < 4; ++n)
            #pragma unroll
            for (int j = 0; j < 4; ++j) acc[m][n][j] = 0.0f;

    for (int k0 = 0; k0 < DM; k0 += 64) {
        #pragma unroll
        for (int qi = 0; qi < 4; ++qi) {
            async_copy16(Ab + soff[qi] + k0, As + doff[qi]);
            async_copy16(Bb + soff[qi] + k0, Bs + doff[qi]);
        }
        __syncthreads();
        #pragma unroll
        for (int hh = 0; hh < 2; ++hh) {
            bf16x8 af[4], bfr[4];
            #pragma unroll
            for (int m = 0; m < 4; ++m) af[m] = *(const bf16x8*)(As + rowA[m] + tsw[hh]);
            #pragma unroll
            for (int n = 0; n < 4; ++n) bfr[n] = *(const bf16x8*)(Bs + rowB[n] + tsw[hh]);
            #pragma unroll
            for (int m = 0; m < 4; ++m)
                #pragma unroll
                for (int n = 0; n < 4; ++n)
                    acc[m][n] = __builtin_amdgcn_mfma_f32_16x16x32_bf16(af[m], bfr[n], acc[m][n], 0, 0, 0);
        }
        __syncthreads();
    }
    // epilogue: bias + exact gelu -> bf16 h
    float bb[4];
    #pragma unroll
    for (int n = 0; n < 4; ++n) bb[n] = b1[(size_t)e * DF + n0 + wn * 64 + n * 16 + r];
    #pragma unroll
    for (int m = 0; m < 4; ++m) {
        #pragma unroll
        for (int i = 0; i < 4; ++i) {
            int rowi = row0 + wm * 64 + m * 16 + g * 4 + i;
            __hip_bfloat16* hr = h + (size_t)rowi * DF + n0 + wn * 64 + r;
            #pragma unroll
            for (int n = 0; n < 4; ++n) {
                float v = acc[m][n][i] + bb[n];
                float ge = 0.5f * v * (1.0f + erff(v * 0.70710678118654752f));
                hr[n * 16] = __float2bfloat16(ge);
            }
        }
    }
}

// GEMM2: out[t] += v * (h @ w2 + b2), K=DF, N=DM
__global__ __launch_bounds__(256) void gemm2_kernel(
    const __hip_bfloat16* __restrict__ h, const __hip_bfloat16* __restrict__ w2t,
    const float* __restrict__ b2, float* __restrict__ out,
    const int* __restrict__ offs, const int* __restrict__ cnt,
    const int* __restrict__ tok, const float* __restrict__ wgt) {
    __shared__ __attribute__((aligned(128))) __hip_bfloat16 As[128 * 64];
    __shared__ __attribute__((aligned(128))) __hip_bfloat16 Bs[128 * 64];
    const int NXT = DM / 128;                 // 8 n-tiles
    const int nwg = NXT * (RCAP / 128);       // 576, %8==0
    int wg = (int)blockIdx.x;
    int id = (wg & 7) * (nwg >> 3) + (wg >> 3);
    const int bx = id % NXT, by = id / NXT;
    const int row0 = by * 128;
    const int total = offs[NE];
    if (row0 >= total) return;
    int e = 0;
    while (row0 >= offs[e + 1]) ++e;
    if (row0 >= offs[e] + cnt[e]) return;
    const int n0 = bx * 128;
    const __hip_bfloat16* Ab = h + (size_t)row0 * DF;
    const __hip_bfloat16* Bb = w2t + (size_t)e * DM * DF + (size_t)n0 * DF;

    const int tid = threadIdx.x, lane = tid & 63, wave = tid >> 6;
    const int wm = wave >> 1, wn = wave & 1, g = lane >> 4, r = lane & 15;
    const int rr = lane >> 3;
    const int kx = (((lane & 7) ^ rr) << 3);
    size_t soff[4]; int doff[4];
    #pragma unroll
    for (int qi = 0; qi < 4; ++qi) {
        int q = wave * 4 + qi;
        soff[qi] = (size_t)(q * 8 + rr) * DF + kx;
        doff[qi] = q * 512 + lane * 8;
    }
    int rowA[4], rowB[4], tsw[2];
    #pragma unroll
    for (int m = 0; m < 4; ++m) rowA[m] = (wm * 64 + m * 16 + r) * 64;
    #pragma unroll
    for (int n = 0; n < 4; ++n) rowB[n] = (wn * 64 + n * 16 + r) * 64;
    tsw[0] = ((g ^ (r & 7)) << 3);
    tsw[1] = (((4 + g) ^ (r & 7)) << 3);

    f32x4 acc[4][4];
    #pragma unroll
    for (int m = 0; m < 4; ++m)
        #pragma unroll
        for (int n = 0; n < 4; ++n)
            #pragma unroll
            for (int j = 0; j < 4; ++j) acc[m][n][j] = 0.0f;

    for (int k0 = 0; k0 < DF; k0 += 64) {
        #pragma unroll
        for (int qi = 0; qi < 4; ++qi) {
            async_copy16(Ab + soff[qi] + k0, As + doff[qi]);
            async_copy16(Bb + soff[qi] + k0, Bs + doff[qi]);
        }
        __syncthreads();
        #pragma unroll
        for (int hh = 0; hh < 2; ++hh) {
            bf16x8 af[4], bfr[4];
            #pragma unroll
            for (int m = 0; m < 4; ++m) af[m] = *(const bf16x8*)(As + rowA[m] + tsw[hh]);
            #pragma unroll
            for (int n = 0; n < 4; ++n) bfr[n] = *(const bf16x8*)(Bs + rowB[n] + tsw[hh]);
            #pragma unroll
            for (int m = 0; m < 4; ++m)
                #pragma unroll
                for (int n = 0; n < 4; ++n)
                    acc[m][n] = __builtin_amdgcn_mfma_f32_16x16x32_bf16(af[m], bfr[n], acc[m][n], 0, 0, 0);
        }
        __syncthreads();
    }
    // epilogue: weighted scatter-add with bias
    float bb[4];
    #pragma unroll
    for (int n = 0; n < 4; ++n) bb[n] = b2[(size_t)e * DM + n0 + wn * 64 + n * 16 + r];
    #pragma unroll
    for (int m = 0; m < 4; ++m) {
        #pragma unroll
        for (int i = 0; i < 4; ++i) {
            int rowi = row0 + wm * 64 + m * 16 + g * 4 + i;
            int t = tok[rowi];
            if (t < 0) continue;
            float wv = wgt[rowi];
            float* orow = out + (size_t)t * DM + n0 + wn * 64 + r;
            #pragma unroll
            for (int n = 0; n < 4; ++n)
                atomicAdd(orow + n * 16, wv * (acc[m][n][i] + bb[n]));
        }
    }
}

// ---------------- launch ----------------
extern "C" void kernel_launch(void* const* d_in, const int* in_sizes, int n_in,
                              void* d_out, int out_size, void* d_ws, size_t ws_size,
                              hipStream_t stream) {
    const float* x  = (const float*)d_in[0];
    const float* gw = (const float*)d_in[1];
    const float* gb = (const float*)d_in[2];
    const float* w1 = (const float*)d_in[3];
    const float* b1 = (const float*)d_in[4];
    const float* w2 = (const float*)d_in[5];
    const float* b2 = (const float*)d_in[6];

    float* out    = (float*)d_out;           // [NT*DM]
    float* disp   = out + OUT_N;             // [NT*NE]
    float* counts = disp + DISP_N;           // [NE]

    char* ws = (char*)d_ws;
    int*   cnt  = (int*)(ws + WS_CNT);
    int*   fill = (int*)(ws + WS_FILL);
    int*   offs = (int*)(ws + WS_OFFS);
    int*   tok  = (int*)(ws + WS_TOK);
    float* wgt  = (float*)(ws + WS_WGT);
    int*   tope = (int*)(ws + WS_TOPE);
    float* topv = (float*)(ws + WS_TOPV);
    __hip_bfloat16* w1t = (__hip_bfloat16*)(ws + WS_W1T);
    __hip_bfloat16* w2t = (__hip_bfloat16*)(ws + WS_W2T);
    __hip_bfloat16* xg  = (__hip_bfloat16*)(ws + WS_XG);
    __hip_bfloat16* h   = (__hip_bfloat16*)(ws + WS_H);

    init_kernel<<<4096, 256, 0, stream>>>(out, cnt, fill, tok);
    // w1: per-expert [DM][DF] -> [DF][DM]
    transpose_cast2<<<dim3(DF / 64, DM / 64, NE), 256, 0, stream>>>(w1, w1t, DM, DF);
    // w2: per-expert [DF][DM] -> [DM][DF]
    transpose_cast2<<<dim3(DM / 64, DF / 64, NE), 256, 0, stream>>>(w2, w2t, DF, DM);
    gate_kernel<<<NT, 64, 0, stream>>>(x, gw, gb, disp, counts, cnt, tope, topv);
    scan_kernel<<<1, 64, 0, stream>>>(cnt, offs);
    build_kernel<<<NT / 256, 256, 0, stream>>>(tope, topv, offs, fill, tok, wgt);
    gather_kernel<<<RCAP, 256, 0, stream>>>(x, tok, xg);
    gemm1_kernel<<<(DF / 128) * (RCAP / 128), 256, 0, stream>>>(xg, w1t, b1, h, offs, cnt);
    gemm2_kernel<<<(DM / 128) * (RCAP / 128), 256, 0, stream>>>(h, w2t, b2, out, offs, cnt, tok, wgt);
}

// Round 3
// 770.829 us; speedup vs baseline: 1.0580x; 1.0580x over previous
//
#include <hip/hip_runtime.h>
#include <hip/hip_bf16.h>
#include <math.h>

// Problem constants
#define DM    1024          // d_model
#define NE    8             // experts
#define DF    4096          // d_ff
#define NT    4096          // tokens = B*S = 2*2048
#define RCAP  9216          // padded row capacity: 8192 + 8*128
#define OUT_N   (NT*DM)     // 4,194,304
#define DISP_N  (NT*NE)     // 32,768
#define TOTAL_OUT (OUT_N + DISP_N + NE)

typedef __attribute__((ext_vector_type(4))) float f32x4;
typedef __attribute__((ext_vector_type(8))) short bf16x8;

// ---------------- ws layout (bytes) ----------------
#define WS_CNT    0            // int[8]
#define WS_FILL   32           // int[8]
#define WS_OFFS   64           // int[9]
#define WS_TOK    128          // int[RCAP]
#define WS_WGT    (WS_TOK + RCAP*4)          // float[RCAP]
#define WS_TOPE   (WS_WGT + RCAP*4)          // int[NT*2]
#define WS_TOPV   (WS_TOPE + NT*2*4)         // float[NT*2]
#define WS_W1T    (((WS_TOPV + NT*2*4) + 255) & ~255ul)   // bf16[NE][DF][DM]
#define WS_W2T    (WS_W1T + (size_t)NE*DF*DM*2)           // bf16[NE][DM][DF]
#define WS_XG     (WS_W2T + (size_t)NE*DM*DF*2)           // bf16[RCAP][DM]
#define WS_H      (WS_XG  + (size_t)RCAP*DM*2)            // bf16[RCAP][DF]

__device__ __forceinline__ void async_copy16(const __hip_bfloat16* g, __hip_bfloat16* l) {
    __builtin_amdgcn_global_load_lds(
        (const __attribute__((address_space(1))) unsigned int*)g,
        (__attribute__((address_space(3))) unsigned int*)l, 16, 0, 0);
}

// fast GELU: tanh form, |err vs exact| ~1e-3 rel << bf16 rounding; no erff (saves ~25 VALU ops/call)
__device__ __forceinline__ float gelu_f(float v) {
    float u = v * (0.7978845608028654f + 0.044715f * 0.7978845608028654f * v * v);
    float t = __expf(2.0f * u);            // exp overflow -> inf handled below
    float th = 1.0f - 2.0f / (t + 1.0f);   // t=inf -> 1, t=0 -> -1
    return 0.5f * v * (1.0f + th);
}

// ---------------- init: zero d_out, reset routing scratch ----------------
__global__ void init_kernel(float* __restrict__ out, int* __restrict__ cnt,
                            int* __restrict__ fill, int* __restrict__ tok) {
    int gid = blockIdx.x * blockDim.x + threadIdx.x;
    int stride = gridDim.x * blockDim.x;
    for (int i = gid; i < TOTAL_OUT; i += stride) out[i] = 0.0f;
    if (gid < RCAP) tok[gid] = -1;
    if (gid < NE) { cnt[gid] = 0; fill[gid] = 0; }
}

// ---------------- transpose+cast v2: in[e][R][C] f32 -> out[e][C][R] bf16 ----------------
__global__ __launch_bounds__(256) void transpose_cast2(const float* __restrict__ in,
                                                       __hip_bfloat16* __restrict__ outp,
                                                       int R, int C) {
    __shared__ ushort tile[64][72];
    int e = blockIdx.z;
    int c0 = blockIdx.x * 64, r0 = blockIdx.y * 64;
    const float* ib = in + (size_t)e * R * C;
    ushort* ob = (ushort*)outp + (size_t)e * R * C;
    int tx = threadIdx.x & 15, ty = threadIdx.x >> 4;   // 16 x 16
    #pragma unroll
    for (int j = 0; j < 4; ++j) {
        int row = ty + 16 * j;
        float4 v = *(const float4*)(ib + (size_t)(r0 + row) * C + c0 + tx * 4);
        tile[tx * 4 + 0][row] = __bfloat16_as_ushort(__float2bfloat16(v.x));
        tile[tx * 4 + 1][row] = __bfloat16_as_ushort(__float2bfloat16(v.y));
        tile[tx * 4 + 2][row] = __bfloat16_as_ushort(__float2bfloat16(v.z));
        tile[tx * 4 + 3][row] = __bfloat16_as_ushort(__float2bfloat16(v.w));
    }
    __syncthreads();
    #pragma unroll
    for (int j = 0; j < 4; ++j) {
        int cc = ty + 16 * j;
        *(ushort4*)(ob + (size_t)(c0 + cc) * R + r0 + tx * 4) = *(const ushort4*)&tile[cc][tx * 4];
    }
}

// ---------------- gating: 1 wave per token, f64 logits ----------------
__global__ void gate_kernel(const float* __restrict__ x, const float* __restrict__ gw,
                            const float* __restrict__ gb, float* __restrict__ disp,
                            float* __restrict__ counts, int* __restrict__ cnt,
                            int* __restrict__ tope, float* __restrict__ topv) {
    int t = blockIdx.x;
    int l = threadIdx.x;   // 64
    const float* xr = x + (size_t)t * DM;
    double p[NE];
    #pragma unroll
    for (int e = 0; e < NE; ++e) p[e] = 0.0;
    for (int i = 0; i < DM / 64; ++i) {
        int d = l + 64 * i;
        double xv = (double)xr[d];
        const float* gr = gw + (size_t)d * NE;
        #pragma unroll
        for (int e = 0; e < NE; ++e) p[e] += xv * (double)gr[e];
    }
    #pragma unroll
    for (int off = 32; off > 0; off >>= 1) {
        #pragma unroll
        for (int e = 0; e < NE; ++e) p[e] += __shfl_xor(p[e], off, 64);
    }
    if (l == 0) {
        double lg[NE];
        double m = -1e300;
        #pragma unroll
        for (int e = 0; e < NE; ++e) { lg[e] = p[e] + (double)gb[e]; m = fmax(m, lg[e]); }
        double s = 0.0;
        #pragma unroll
        for (int e = 0; e < NE; ++e) s += exp(lg[e] - m);
        int e1 = 0;
        #pragma unroll
        for (int e = 1; e < NE; ++e) if (lg[e] > lg[e1]) e1 = e;
        int e2 = (e1 == 0) ? 1 : 0;
        #pragma unroll
        for (int e = 0; e < NE; ++e) if (e != e1 && lg[e] > lg[e2]) e2 = e;
        float v1 = (float)(exp(lg[e1] - m) / s);
        float v2 = (float)(exp(lg[e2] - m) / s);
        float* dr = disp + (size_t)t * NE;
        #pragma unroll
        for (int e = 0; e < NE; ++e) dr[e] = 0.0f;
        dr[e1] = v1; dr[e2] = v2;
        atomicAdd(&counts[e1], v1);
        atomicAdd(&counts[e2], v2);
        atomicAdd(&cnt[e1], 1);
        atomicAdd(&cnt[e2], 1);
        tope[2 * t] = e1;     topv[2 * t] = v1;
        tope[2 * t + 1] = e2; topv[2 * t + 1] = v2;
    }
}

// ---------------- scan: 128-aligned exclusive prefix ----------------
__global__ void scan_kernel(const int* __restrict__ cnt, int* __restrict__ offs) {
    if (threadIdx.x == 0 && blockIdx.x == 0) {
        int o = 0;
        for (int e = 0; e < NE; ++e) {
            offs[e] = o;
            o += (cnt[e] + 127) & ~127;
        }
        offs[NE] = o;
    }
}

// ---------------- build per-expert row lists ----------------
__global__ void build_kernel(const int* __restrict__ tope, const float* __restrict__ topv,
                             const int* __restrict__ offs, int* __restrict__ fill,
                             int* __restrict__ tok, float* __restrict__ wgt) {
    int t = blockIdx.x * blockDim.x + threadIdx.x;
    if (t >= NT) return;
    #pragma unroll
    for (int s = 0; s < 2; ++s) {
        int e = tope[2 * t + s];
        int pos = atomicAdd(&fill[e], 1);
        int row = offs[e] + pos;
        tok[row] = t;
        wgt[row] = topv[2 * t + s];
    }
}

// ---------------- gather x rows -> bf16 ----------------
__global__ void gather_kernel(const float* __restrict__ x, const int* __restrict__ tok,
                              __hip_bfloat16* __restrict__ xg) {
    int row = blockIdx.x;
    int t = tok[row];
    if (t < 0) return;
    int i = threadIdx.x;   // 256, 4 elems each
    const float4 v = ((const float4*)(x + (size_t)t * DM))[i];
    ushort4 o;
    o.x = __bfloat16_as_ushort(__float2bfloat16(v.x));
    o.y = __bfloat16_as_ushort(__float2bfloat16(v.y));
    o.z = __bfloat16_as_ushort(__float2bfloat16(v.z));
    o.w = __bfloat16_as_ushort(__float2bfloat16(v.w));
    ((ushort4*)(xg + (size_t)row * DM))[i] = o;
}

// ================= GEMM core: m97 structure (128x128 tile, BK=32, 4 waves) =================
// A: bf16 [rows][K]; B: bf16 [N][K] (pre-transposed). XCD-chunked block swizzle (T1).

// GEMM1: h = gelu(xg @ w1 + b1), K=DM, N=DF
__global__ __launch_bounds__(256) void gemm1_kernel(
    const __hip_bfloat16* __restrict__ xg, const __hip_bfloat16* __restrict__ w1t,
    const float* __restrict__ b1, __hip_bfloat16* __restrict__ h,
    const int* __restrict__ offs, const int* __restrict__ cnt) {
    __shared__ __hip_bfloat16 As[128 * 32];
    __shared__ __hip_bfloat16 Bs[128 * 32];
    const int NXT = DF / 128;                 // 32
    const int nwg = NXT * (RCAP / 128);       // 2304, %8==0
    int wg = (int)blockIdx.x;
    int id = (wg & 7) * (nwg >> 3) + (wg >> 3);   // XCD-chunked (bijective, nwg%8==0)
    const int bx = id % NXT, by = id / NXT;       // consecutive ids share the A-panel (by)
    const int row0 = by * 128;
    const int total = offs[NE];
    if (row0 >= total) return;
    int e = 0;
    while (row0 >= offs[e + 1]) ++e;
    if (row0 >= offs[e] + cnt[e]) return;     // tile entirely padding
    const int n0 = bx * 128;
    const __hip_bfloat16* Ab = xg + (size_t)row0 * DM;
    const __hip_bfloat16* Bb = w1t + (size_t)e * DF * DM + (size_t)n0 * DM;

    const int tid = threadIdx.x, lane = tid & 63, wave = tid >> 6;
    const int wm = wave >> 1, wn = wave & 1, g = lane >> 4, r = lane & 15;
    const int c1 = tid, c2 = tid + 256;

    f32x4 acc[4][4];
    #pragma unroll
    for (int m = 0; m < 4; ++m)
        #pragma unroll
        for (int n = 0; n < 4; ++n)
            #pragma unroll
            for (int j = 0; j < 4; ++j) acc[m][n][j] = 0.0f;

    for (int k0 = 0; k0 < DM; k0 += 32) {
        async_copy16(Ab + (size_t)(c1 >> 2) * DM + k0 + (c1 & 3) * 8, As + c1 * 8);
        async_copy16(Ab + (size_t)(c2 >> 2) * DM + k0 + (c2 & 3) * 8, As + c2 * 8);
        async_copy16(Bb + (size_t)(c1 >> 2) * DM + k0 + (c1 & 3) * 8, Bs + c1 * 8);
        async_copy16(Bb + (size_t)(c2 >> 2) * DM + k0 + (c2 & 3) * 8, Bs + c2 * 8);
        __syncthreads();
        bf16x8 af[4], bfr[4];
        #pragma unroll
        for (int m = 0; m < 4; ++m)
            af[m] = *(const bf16x8*)(As + (wm * 64 + m * 16 + r) * 32 + g * 8);
        #pragma unroll
        for (int n = 0; n < 4; ++n)
            bfr[n] = *(const bf16x8*)(Bs + (wn * 64 + n * 16 + r) * 32 + g * 8);
        #pragma unroll
        for (int m = 0; m < 4; ++m)
            #pragma unroll
            for (int n = 0; n < 4; ++n)
                acc[m][n] = __builtin_amdgcn_mfma_f32_16x16x32_bf16(af[m], bfr[n], acc[m][n], 0, 0, 0);
        __syncthreads();
    }
    // epilogue: bias + fast gelu -> bf16 h
    float bb[4];
    #pragma unroll
    for (int n = 0; n < 4; ++n) bb[n] = b1[(size_t)e * DF + n0 + wn * 64 + n * 16 + r];
    #pragma unroll
    for (int m = 0; m < 4; ++m) {
        #pragma unroll
        for (int i = 0; i < 4; ++i) {
            int rowi = row0 + wm * 64 + m * 16 + g * 4 + i;
            __hip_bfloat16* hr = h + (size_t)rowi * DF + n0 + wn * 64 + r;
            #pragma unroll
            for (int n = 0; n < 4; ++n)
                hr[n * 16] = __float2bfloat16(gelu_f(acc[m][n][i] + bb[n]));
        }
    }
}

// GEMM2: out[t] += v * (h @ w2 + b2), K=DF split 4 ways, N=DM
#define KSP 4
__global__ __launch_bounds__(256) void gemm2_kernel(
    const __hip_bfloat16* __restrict__ h, const __hip_bfloat16* __restrict__ w2t,
    const float* __restrict__ b2, float* __restrict__ out,
    const int* __restrict__ offs, const int* __restrict__ cnt,
    const int* __restrict__ tok, const float* __restrict__ wgt) {
    __shared__ __hip_bfloat16 As[128 * 32];
    __shared__ __hip_bfloat16 Bs[128 * 32];
    const int NXT = DM / 128;                     // 8
    const int nwg = NXT * (RCAP / 128) * KSP;     // 2304, %8==0
    int wg = (int)blockIdx.x;
    int id = (wg & 7) * (nwg >> 3) + (wg >> 3);
    const int bx = id & 7;                        // id = ((by*KSP+ksp)*8)|bx
    const int ksp = (id >> 3) & (KSP - 1);        // consecutive ids share A-chunk (by,ksp)
    const int by = id >> 5;
    const int row0 = by * 128;
    const int total = offs[NE];
    if (row0 >= total) return;
    int e = 0;
    while (row0 >= offs[e + 1]) ++e;
    if (row0 >= offs[e] + cnt[e]) return;
    const int n0 = bx * 128;
    const __hip_bfloat16* Ab = h + (size_t)row0 * DF;
    const __hip_bfloat16* Bb = w2t + (size_t)e * DM * DF + (size_t)n0 * DF;

    const int tid = threadIdx.x, lane = tid & 63, wave = tid >> 6;
    const int wm = wave >> 1, wn = wave & 1, g = lane >> 4, r = lane & 15;
    const int c1 = tid, c2 = tid + 256;

    f32x4 acc[4][4];
    #pragma unroll
    for (int m = 0; m < 4; ++m)
        #pragma unroll
        for (int n = 0; n < 4; ++n)
            #pragma unroll
            for (int j = 0; j < 4; ++j) acc[m][n][j] = 0.0f;

    const int kbeg = ksp * (DF / KSP), kend = kbeg + DF / KSP;   // 1024-long chunk
    for (int k0 = kbeg; k0 < kend; k0 += 32) {
        async_copy16(Ab + (size_t)(c1 >> 2) * DF + k0 + (c1 & 3) * 8, As + c1 * 8);
        async_copy16(Ab + (size_t)(c2 >> 2) * DF + k0 + (c2 & 3) * 8, As + c2 * 8);
        async_copy16(Bb + (size_t)(c1 >> 2) * DF + k0 + (c1 & 3) * 8, Bs + c1 * 8);
        async_copy16(Bb + (size_t)(c2 >> 2) * DF + k0 + (c2 & 3) * 8, Bs + c2 * 8);
        __syncthreads();
        bf16x8 af[4], bfr[4];
        #pragma unroll
        for (int m = 0; m < 4; ++m)
            af[m] = *(const bf16x8*)(As + (wm * 64 + m * 16 + r) * 32 + g * 8);
        #pragma unroll
        for (int n = 0; n < 4; ++n)
            bfr[n] = *(const bf16x8*)(Bs + (wn * 64 + n * 16 + r) * 32 + g * 8);
        #pragma unroll
        for (int m = 0; m < 4; ++m)
            #pragma unroll
            for (int n = 0; n < 4; ++n)
                acc[m][n] = __builtin_amdgcn_mfma_f32_16x16x32_bf16(af[m], bfr[n], acc[m][n], 0, 0, 0);
        __syncthreads();
    }
    // epilogue: weighted scatter-add; bias only from the ksp==0 chunk
    float bb[4];
    #pragma unroll
    for (int n = 0; n < 4; ++n)
        bb[n] = (ksp == 0) ? b2[(size_t)e * DM + n0 + wn * 64 + n * 16 + r] : 0.0f;
    #pragma unroll
    for (int m = 0; m < 4; ++m) {
        #pragma unroll
        for (int i = 0; i < 4; ++i) {
            int rowi = row0 + wm * 64 + m * 16 + g * 4 + i;
            int t = tok[rowi];
            if (t < 0) continue;
            float wv = wgt[rowi];
            float* orow = out + (size_t)t * DM + n0 + wn * 64 + r;
            #pragma unroll
            for (int n = 0; n < 4; ++n)
                atomicAdd(orow + n * 16, wv * (acc[m][n][i] + bb[n]));
        }
    }
}

// ---------------- launch ----------------
extern "C" void kernel_launch(void* const* d_in, const int* in_sizes, int n_in,
                              void* d_out, int out_size, void* d_ws, size_t ws_size,
                              hipStream_t stream) {
    const float* x  = (const float*)d_in[0];
    const float* gw = (const float*)d_in[1];
    const float* gb = (const float*)d_in[2];
    const float* w1 = (const float*)d_in[3];
    const float* b1 = (const float*)d_in[4];
    const float* w2 = (const float*)d_in[5];
    const float* b2 = (const float*)d_in[6];

    float* out    = (float*)d_out;           // [NT*DM]
    float* disp   = out + OUT_N;             // [NT*NE]
    float* counts = disp + DISP_N;           // [NE]

    char* ws = (char*)d_ws;
    int*   cnt  = (int*)(ws + WS_CNT);
    int*   fill = (int*)(ws + WS_FILL);
    int*   offs = (int*)(ws + WS_OFFS);
    int*   tok  = (int*)(ws + WS_TOK);
    float* wgt  = (float*)(ws + WS_WGT);
    int*   tope = (int*)(ws + WS_TOPE);
    float* topv = (float*)(ws + WS_TOPV);
    __hip_bfloat16* w1t = (__hip_bfloat16*)(ws + WS_W1T);
    __hip_bfloat16* w2t = (__hip_bfloat16*)(ws + WS_W2T);
    __hip_bfloat16* xg  = (__hip_bfloat16*)(ws + WS_XG);
    __hip_bfloat16* h   = (__hip_bfloat16*)(ws + WS_H);

    init_kernel<<<4096, 256, 0, stream>>>(out, cnt, fill, tok);
    transpose_cast2<<<dim3(DF / 64, DM / 64, NE), 256, 0, stream>>>(w1, w1t, DM, DF);
    transpose_cast2<<<dim3(DM / 64, DF / 64, NE), 256, 0, stream>>>(w2, w2t, DF, DM);
    gate_kernel<<<NT, 64, 0, stream>>>(x, gw, gb, disp, counts, cnt, tope, topv);
    scan_kernel<<<1, 64, 0, stream>>>(cnt, offs);
    build_kernel<<<NT / 256, 256, 0, stream>>>(tope, topv, offs, fill, tok, wgt);
    gather_kernel<<<RCAP, 256, 0, stream>>>(x, tok, xg);
    gemm1_kernel<<<(DF / 128) * (RCAP / 128), 256, 0, stream>>>(xg, w1t, b1, h, offs, cnt);
    gemm2_kernel<<<(DM / 128) * (RCAP / 128) * KSP, 256, 0, stream>>>(h, w2t, b2, out, offs, cnt, tok, wgt);
}